// Round 6
// baseline (1047.597 us; speedup 1.0000x reference)
//
#include <hip/hip_runtime.h>
#include <math.h>

#define BATCH 256
typedef unsigned int uint;
typedef unsigned short ushort;
typedef _Float16 h2_t __attribute__((ext_vector_type(2)));

// v_pk_fma_f16: per 16-bit lane c += a*b (f16 accumulate, FULL rate = 2 cyc,
// unlike v_dot2_f32_f16 / f32-accum packed ops which issue at 4 cyc — R5 lesson).
__device__ __forceinline__ h2_t pkfma(uint a, uint b, h2_t c) {
  return __builtin_elementwise_fma(__builtin_bit_cast(h2_t, a),
                                   __builtin_bit_cast(h2_t, b), c);
}
__device__ __forceinline__ h2_t h2zero() { return __builtin_bit_cast(h2_t, 0u); }

__device__ __forceinline__ ushort f2h(float f) {
  _Float16 h = (_Float16)f;
  return __builtin_bit_cast(ushort, h);
}

// x fp32 [256][P] -> xt f16 [P][256], 64x64 LDS tiles
__global__ __launch_bounds__(256) void transpose_kernel(
    const float* __restrict__ x, ushort* __restrict__ xt, int P) {
  __shared__ float tile[64][65];
  int p0 = blockIdx.x * 64, b0 = blockIdx.y * 64;
  int tx = threadIdx.x & 63, ty = threadIdx.x >> 6;
#pragma unroll
  for (int r = 0; r < 64; r += 4) {
    int pp = p0 + tx;
    if (pp < P) tile[tx][ty + r] = x[(size_t)(b0 + ty + r) * (size_t)P + pp];
  }
  __syncthreads();
#pragma unroll
  for (int r = 0; r < 64; r += 4) {
    int pl = ty + r, pp = p0 + pl;
    if (pp < P) xt[(size_t)pp * BATCH + b0 + tx] = f2h(tile[pl][tx]);
  }
}

// Direct 4D conv + bias + relu. f16 activations, v_pk_fma_f16 inner product
// paired over output-w (weight splat), two-level accumulation:
//   f16x2 partials (<=32-term chains) -> f32 masters, flushed every 2 kd.
// Odd WT padded to WTP (pad slot computed, never stored; overread stays in ws).
// R3 lesson: no min-wave launch_bounds. R4/R5 tiling kept.
template <int CIN, int COUT, int CO_PER, int KK, int TI, int HT, int WT>
__global__ __launch_bounds__(256) void conv_relu(
    const ushort* __restrict__ xin, const float* __restrict__ wgt,
    const float* __restrict__ bias, ushort* __restrict__ out) {
  constexpr int WO = TI - KK + 1;
  constexpr int HTILES = WO / HT;
  constexpr int WTILES = WO / WT;
  constexpr int WTP = (WT + 1) / 2 * 2;  // even-padded width tile
  constexpr int PAIRS = WTP / 2;
  constexpr int XV = WTP + KK - 1;       // input row span (pad-extended)
  constexpr int K4 = KK * KK * KK * KK;
  constexpr int NWS = CO_PER * CIN * K4;
  constexpr int sH = TI * BATCH, sD = TI * TI * BATCH,
                sT = TI * TI * TI * BATCH, sC = TI * TI * TI * TI * BATCH;
  constexpr int oH = WO * BATCH, oD = WO * WO * BATCH,
                oT = WO * WO * WO * BATCH, oC = WO * WO * WO * WO * BATCH;

  const int htile = blockIdx.x % HTILES;
  const int wtile = (blockIdx.x / HTILES) % WTILES;
  const int cog = blockIdx.x / (HTILES * WTILES);
  const int co0 = cog * CO_PER;

  __shared__ uint wl[NWS];  // f16 weight splat {w,w}
  for (int i = threadIdx.x; i < NWS; i += 256) {
    uint hw = (uint)f2h(wgt[co0 * CIN * K4 + i]);
    wl[i] = hw | (hw << 16);
  }
  __syncthreads();

  const int d = blockIdx.y, t = blockIdx.z;
  const int h0 = htile * HT, w0 = wtile * WT;
  const int b = threadIdx.x;

  float facc[HT][CO_PER][WTP];
  h2_t hacc[HT][CO_PER][PAIRS];
#pragma unroll
  for (int hh = 0; hh < HT; hh++)
#pragma unroll
    for (int co = 0; co < CO_PER; co++) {
      float bv = bias[co0 + co];
#pragma unroll
      for (int j = 0; j < WTP; j++) facc[hh][co][j] = bv;
#pragma unroll
      for (int p = 0; p < PAIRS; p++) hacc[hh][co][p] = h2zero();
    }

#pragma unroll 1
  for (int ci = 0; ci < CIN; ci++)
#pragma unroll 1
    for (int kt = 0; kt < KK; kt++)
#pragma unroll 1
      for (int kd = 0; kd < KK; kd++) {
        const ushort* base =
            xin + ci * sC + (t + kt) * sT + (d + kd) * sD + w0 * BATCH + b;
#pragma unroll
        for (int r = 0; r < KK + HT - 1; r++) {
          const ushort* row = base + (h0 + r) * sH;
          uint xv[XV];
#pragma unroll
          for (int j = 0; j < XV; j++) xv[j] = (uint)row[j * BATCH];  // coalesced
          uint pk[XV - 1];  // pk[i] = packed {x[i], x[i+1]}
#pragma unroll
          for (int i = 0; i < XV - 1; i++) pk[i] = xv[i] | (xv[i + 1] << 16);
#pragma unroll
          for (int hh = 0; hh < HT; hh++) {
            const int kh = r - hh;  // compile-time after full unroll
            if (kh >= 0 && kh < KK) {
#pragma unroll
              for (int co = 0; co < CO_PER; co++)
#pragma unroll
                for (int kw = 0; kw < KK; kw++) {
                  const uint wv =
                      wl[((((co * CIN + ci) * KK + kt) * KK + kd) * KK + kh) * KK + kw];
#pragma unroll
                  for (int p = 0; p < PAIRS; p++)
                    hacc[hh][co][p] = pkfma(pk[2 * p + kw], wv, hacc[hh][co][p]);
                }
            }
          }
        }
        // flush f16 partials -> f32 masters every 2 kd (and at the last kd)
        if ((kd & 1) || kd == KK - 1) {
#pragma unroll
          for (int hh = 0; hh < HT; hh++)
#pragma unroll
            for (int co = 0; co < CO_PER; co++)
#pragma unroll
              for (int p = 0; p < PAIRS; p++) {
                facc[hh][co][2 * p]     += (float)hacc[hh][co][p][0];
                facc[hh][co][2 * p + 1] += (float)hacc[hh][co][p][1];
                hacc[hh][co][p] = h2zero();
              }
        }
      }

#pragma unroll
  for (int hh = 0; hh < HT; hh++)
#pragma unroll
    for (int co = 0; co < CO_PER; co++)
#pragma unroll
      for (int j = 0; j < WT; j++) {  // WT, not WTP: pad slot dropped
        float v = facc[hh][co][j];
        v = v > 0.f ? v : 0.f;
        out[(co0 + co) * oC + t * oT + d * oD + (h0 + hh) * oH +
            (w0 + j) * BATCH + b] = f2h(v);
      }
}

// h5 f16 [1280][256] (k-major: co,t,d,h,w). One block per output neuron o.
__global__ __launch_bounds__(256) void fc1_kernel(
    const ushort* __restrict__ h, const float* __restrict__ w,
    const float* __restrict__ bias, float* __restrict__ out) {
  const int o = blockIdx.x, b = threadIdx.x;
  const float* wr = w + o * 1280;
  float a0 = 0.f, a1 = 0.f, a2 = 0.f, a3 = 0.f;
#pragma unroll 4
  for (int k = 0; k < 1280; k += 4) {
    a0 = fmaf((float)__builtin_bit_cast(_Float16, h[(k + 0) * BATCH + b]), wr[k + 0], a0);
    a1 = fmaf((float)__builtin_bit_cast(_Float16, h[(k + 1) * BATCH + b]), wr[k + 1], a1);
    a2 = fmaf((float)__builtin_bit_cast(_Float16, h[(k + 2) * BATCH + b]), wr[k + 2], a2);
    a3 = fmaf((float)__builtin_bit_cast(_Float16, h[(k + 3) * BATCH + b]), wr[k + 3], a3);
  }
  float acc = (a0 + a1) + (a2 + a3) + bias[o];
  out[o * BATCH + b] = acc > 0.f ? acc : 0.f;
}

// r: [33][256] -> d_out[256] = sigmoid(w.r + b)
__global__ __launch_bounds__(256) void fc2_kernel(
    const float* __restrict__ r, const float* __restrict__ w,
    const float* __restrict__ bias, float* __restrict__ out) {
  const int b = threadIdx.x;
  float acc = bias[0];
#pragma unroll
  for (int o = 0; o < 33; o++) acc = fmaf(r[o * BATCH + b], w[o], acc);
  out[b] = 1.f / (1.f + expf(-acc));
}

extern "C" void kernel_launch(void* const* d_in, const int* in_sizes, int n_in,
                              void* d_out, int out_size, void* d_ws, size_t ws_size,
                              hipStream_t stream) {
  const float* x    = (const float*)d_in[0];
  const float* w1   = (const float*)d_in[1];
  const float* b1   = (const float*)d_in[2];
  const float* w2   = (const float*)d_in[3];
  const float* b2   = (const float*)d_in[4];
  const float* w3   = (const float*)d_in[5];
  const float* b3   = (const float*)d_in[6];
  const float* w4   = (const float*)d_in[7];
  const float* b4   = (const float*)d_in[8];
  const float* w5   = (const float*)d_in[9];
  const float* b5   = (const float*)d_in[10];
  const float* fc1w = (const float*)d_in[11];
  const float* fc1b = (const float*)d_in[12];
  const float* fc2w = (const float*)d_in[13];
  const float* fc2b = (const float*)d_in[14];
  float* out = (float*)d_out;

  // Workspace: two ushort regions ping-pong. R0: xt,h2,h4 ; R1: h1,h3,h5 ;
  // fc1out fp32 above both.
  ushort* wsu = (ushort*)d_ws;
  ushort* R0 = wsu;
  ushort* R1 = wsu + 32000000;
  ushort* xt = R0;
  ushort* h1 = R1;
  ushort* h2 = R0;
  ushort* h3 = R1;
  ushort* h4 = R0;
  ushort* h5 = R1;
  float* fo = (float*)(wsu + 64000000);

  const int P = 104976;  // 18^4
  transpose_kernel<<<dim3((P + 63) / 64, 4), 256, 0, stream>>>(x, xt, P);

  // <CIN, COUT, CO_PER, KK, TI, HT, WT>  grid(HTILES*WTILES*COUT/CO_PER, d, t)
  conv_relu<1, 3, 3, 4, 18, 3, 5><<<dim3(15, 15, 15), 256, 0, stream>>>(xt, w1, b1, h1);
  conv_relu<3, 3, 3, 4, 15, 3, 6><<<dim3(8, 12, 12), 256, 0, stream>>>(h1, w2, b2, h2);
  conv_relu<3, 4, 4, 4, 12, 3, 3><<<dim3(9, 9, 9), 256, 0, stream>>>(h2, w3, b3, h3);
  conv_relu<4, 5, 5, 4, 9, 1, 3><<<dim3(12, 6, 6), 256, 0, stream>>>(h3, w4, b4, h4);
  conv_relu<5, 5, 5, 3, 6, 1, 4><<<dim3(4, 4, 4), 256, 0, stream>>>(h4, w5, b5, h5);

  fc1_kernel<<<33, 256, 0, stream>>>(h5, fc1w, fc1b, fo);
  fc2_kernel<<<1, 256, 0, stream>>>(fo, fc2w, fc2b, out);
}

// Round 7
// 870.509 us; speedup vs baseline: 1.2034x; 1.2034x over previous
//
#include <hip/hip_runtime.h>
#include <math.h>

#define BATCH 256
typedef unsigned int uint;
typedef unsigned short ushort;
typedef _Float16 half8 __attribute__((ext_vector_type(8)));
typedef float f32x4 __attribute__((ext_vector_type(4)));
typedef uint u32x4 __attribute__((ext_vector_type(4)));

#define GLOBAL_AS __attribute__((address_space(1)))
#define LDS_AS __attribute__((address_space(3)))

__device__ __forceinline__ ushort f2h(float f) {
  _Float16 h = (_Float16)f;
  return __builtin_bit_cast(ushort, h);
}

// x fp32 [256][P] -> xt f16 [P][256], 64x64 LDS tiles
__global__ __launch_bounds__(256) void transpose_kernel(
    const float* __restrict__ x, ushort* __restrict__ xt, int P) {
  __shared__ float tile[64][65];
  int p0 = blockIdx.x * 64, b0 = blockIdx.y * 64;
  int tx = threadIdx.x & 63, ty = threadIdx.x >> 6;
#pragma unroll
  for (int r = 0; r < 64; r += 4) {
    int pp = p0 + tx;
    if (pp < P) tile[tx][ty + r] = x[(size_t)(b0 + ty + r) * (size_t)P + pp];
  }
  __syncthreads();
#pragma unroll
  for (int r = 0; r < 64; r += 4) {
    int pl = ty + r, pp = p0 + pl;
    if (pp < P) xt[(size_t)pp * BATCH + b0 + tx] = f2h(tile[pl][tx]);
  }
}

// Build block-Toeplitz B table for one conv layer.
// Bg[chunk][n=16][k=32] f16, chunk=(ci*KK+kt)*KK+kd, k=kh*8+wi, n=dw*COUT+co.
// B[k][n] = w[co][ci][kt][kd][kh][wi-dw] when valid else 0.
template <int CIN, int COUT, int KK, int S>
__global__ __launch_bounds__(256) void build_b(
    const float* __restrict__ w, ushort* __restrict__ Bg) {
  const int chunk = blockIdx.x;
  const int kd = chunk % KK, kt = (chunk / KK) % KK, ci = chunk / (KK * KK);
  for (int e = threadIdx.x; e < 512; e += 256) {
    int n = e >> 5, k = e & 31;
    int kh = k >> 3, wi = k & 7;
    int dw = n / COUT, co = n % COUT;
    int kw = wi - dw;
    float v = 0.f;
    if (n < S * COUT && kh < KK && kw >= 0 && kw < KK)
      v = w[((((co * CIN + ci) * KK + kt) * KK + kd) * KK + kh) * KK + kw];
    Bg[chunk * 512 + n * 32 + k] = f2h(v);
  }
}

// MFMA implicit conv. One block = one (t, d, h-tile of HB, w-tile of S),
// all 256 batch. N = (dw,co) Toeplitz-folded columns; M = batch; K chunks of
// 32 = (kh 0..3 x wi 0..7) per (ci,kt,kd). A staged [row][wi][b] in LDS via
// global_load_lds (4KB contiguous rows), double-buffered; A-frag = 8x
// ds_read_u16 (quad=kh-row, j=wi); B-frag = one dwordx4 from L2-resident Bg.
// Zero-weight pads make OOB/garbage A reads harmless (finite x 0).
template <int CIN, int COUT, int KK, int TI, int S, int HB>
__global__ __launch_bounds__(256) void conv_mfma(
    const ushort* __restrict__ xin, const ushort* __restrict__ Bg,
    const float* __restrict__ bias, ushort* __restrict__ out) {
  constexpr int WO = TI - KK + 1;
  constexpr int HTILES = WO / HB;
  constexpr int NC = CIN * KK * KK;
  constexpr int RS = 4 + HB - 1;   // staged h-rows (KHP=4)
  constexpr int ROWU = 8 * BATCH;  // 2048 ushorts = one [wi=8][b=256] row
  constexpr int sH = TI * BATCH, sD = TI * TI * BATCH,
                sT = TI * TI * TI * BATCH, sC = TI * TI * TI * TI * BATCH;
  constexpr int oH = WO * BATCH, oD = WO * WO * BATCH,
                oT = WO * WO * WO * BATCH, oC = WO * WO * WO * WO * BATCH;

  __shared__ ushort slab[2][RS * ROWU];

  const int ht = blockIdx.x % HTILES;
  const int wt = blockIdx.x / HTILES;
  const int d = blockIdx.y, t = blockIdx.z;
  const int h0 = ht * HB, wb = wt * S;

  const int tid = threadIdx.x;
  const int wave = tid >> 6, lane = tid & 63;
  const int quad = lane >> 4, mm = lane & 15;

  f32x4 acc[HB][4];
#pragma unroll
  for (int dh = 0; dh < HB; dh++)
#pragma unroll
    for (int bt = 0; bt < 4; bt++) acc[dh][bt] = (f32x4){0.f, 0.f, 0.f, 0.f};

  auto stage = [&](int c, int buf) {
    const int kd = c % KK, kt2 = (c / KK) % KK, ci = c / (KK * KK);
    const ushort* base = xin + ci * sC + (t + kt2) * sT + (d + kd) * sD + wb * BATCH;
    for (int r = wave; r < RS; r += 4) {
      const ushort* g = base + (h0 + r) * sH;
      ushort* l = &slab[buf][r * ROWU];
#pragma unroll
      for (int p = 0; p < 4; p++) {
#if __has_builtin(__builtin_amdgcn_global_load_lds)
        __builtin_amdgcn_global_load_lds(
            (const GLOBAL_AS uint*)(const void*)(g + p * 512 + lane * 8),
            (LDS_AS uint*)(void*)(l + p * 512), 16, 0, 0);
#else
        ((u32x4*)(void*)l)[p * 64 + lane] =
            ((const u32x4*)(const void*)g)[p * 64 + lane];
#endif
      }
    }
  };

  stage(0, 0);

  for (int c = 0; c < NC; c++) {
    __syncthreads();  // slab[c&1] ready; everyone done with slab[(c+1)&1]
    if (c + 1 < NC) stage(c + 1, (c + 1) & 1);

    u32x4 braw = *(const u32x4*)(const void*)(Bg + c * 512 + mm * 32 + quad * 8);
    half8 bf = __builtin_bit_cast(half8, braw);
    const int buf = c & 1;

#pragma unroll
    for (int dh = 0; dh < HB; dh++) {
      const ushort* arow = &slab[buf][(dh + quad) * ROWU + mm];
#pragma unroll
      for (int bt = 0; bt < 4; bt++) {
        const int b0 = (wave * 4 + bt) * 16;
        half8 af;
#pragma unroll
        for (int j = 0; j < 8; j++)
          af[j] = __builtin_bit_cast(_Float16, arow[j * BATCH + b0]);
        acc[dh][bt] =
            __builtin_amdgcn_mfma_f32_16x16x32_f16(af, bf, acc[dh][bt], 0, 0, 0);
      }
    }
  }

  // Epilogue: C/D layout col(n)=lane&15, row(m)=quad*4+reg. m = batch offset.
  const int n = mm;
  const int dw = n / COUT, co = n % COUT;
  if (n < S * COUT) {
    const float bv = bias[co];
#pragma unroll
    for (int dh = 0; dh < HB; dh++)
#pragma unroll
      for (int bt = 0; bt < 4; bt++) {
        const int b0 = (wave * 4 + bt) * 16;
        float r0 = acc[dh][bt][0] + bv, r1 = acc[dh][bt][1] + bv;
        float r2 = acc[dh][bt][2] + bv, r3 = acc[dh][bt][3] + bv;
        r0 = r0 > 0.f ? r0 : 0.f; r1 = r1 > 0.f ? r1 : 0.f;
        r2 = r2 > 0.f ? r2 : 0.f; r3 = r3 > 0.f ? r3 : 0.f;
        uint lo = (uint)f2h(r0) | ((uint)f2h(r1) << 16);
        uint hi = (uint)f2h(r2) | ((uint)f2h(r3) << 16);
        ushort* op = out + co * oC + t * oT + d * oD + (h0 + dh) * oH +
                     (wb + dw) * BATCH + b0 + quad * 4;
        uint2 v; v.x = lo; v.y = hi;
        *(uint2*)(void*)op = v;  // 4 consecutive batch f16, 8B aligned
      }
  }
}

// h5 f16 [1280][256] (k-major: co,t,d,h,w). One block per output neuron o.
__global__ __launch_bounds__(256) void fc1_kernel(
    const ushort* __restrict__ h, const float* __restrict__ w,
    const float* __restrict__ bias, float* __restrict__ out) {
  const int o = blockIdx.x, b = threadIdx.x;
  const float* wr = w + o * 1280;
  float a0 = 0.f, a1 = 0.f, a2 = 0.f, a3 = 0.f;
#pragma unroll 4
  for (int k = 0; k < 1280; k += 4) {
    a0 = fmaf((float)__builtin_bit_cast(_Float16, h[(k + 0) * BATCH + b]), wr[k + 0], a0);
    a1 = fmaf((float)__builtin_bit_cast(_Float16, h[(k + 1) * BATCH + b]), wr[k + 1], a1);
    a2 = fmaf((float)__builtin_bit_cast(_Float16, h[(k + 2) * BATCH + b]), wr[k + 2], a2);
    a3 = fmaf((float)__builtin_bit_cast(_Float16, h[(k + 3) * BATCH + b]), wr[k + 3], a3);
  }
  float acc = (a0 + a1) + (a2 + a3) + bias[o];
  out[o * BATCH + b] = acc > 0.f ? acc : 0.f;
}

__global__ __launch_bounds__(256) void fc2_kernel(
    const float* __restrict__ r, const float* __restrict__ w,
    const float* __restrict__ bias, float* __restrict__ out) {
  const int b = threadIdx.x;
  float acc = bias[0];
#pragma unroll
  for (int o = 0; o < 33; o++) acc = fmaf(r[o * BATCH + b], w[o], acc);
  out[b] = 1.f / (1.f + expf(-acc));
}

extern "C" void kernel_launch(void* const* d_in, const int* in_sizes, int n_in,
                              void* d_out, int out_size, void* d_ws, size_t ws_size,
                              hipStream_t stream) {
  const float* x    = (const float*)d_in[0];
  const float* w1   = (const float*)d_in[1];
  const float* b1   = (const float*)d_in[2];
  const float* w2   = (const float*)d_in[3];
  const float* b2   = (const float*)d_in[4];
  const float* w3   = (const float*)d_in[5];
  const float* b3   = (const float*)d_in[6];
  const float* w4   = (const float*)d_in[7];
  const float* b4   = (const float*)d_in[8];
  const float* w5   = (const float*)d_in[9];
  const float* b5   = (const float*)d_in[10];
  const float* fc1w = (const float*)d_in[11];
  const float* fc1b = (const float*)d_in[12];
  const float* fc2w = (const float*)d_in[13];
  const float* fc2b = (const float*)d_in[14];
  float* out = (float*)d_out;

  // Workspace (ushort units). R0: xt,h2,h4 ; R1: h1,h3,h5 ; Bg ; fo.
  // Staging may overread ~10KB past buffer ends -> margins included.
  ushort* wsu = (ushort*)d_ws;
  ushort* R0 = wsu;                    // needs 26,873,856 (+margin)
  ushort* R1 = wsu + 27300000;         // needs 38,880,000 (+margin)
  ushort* Bgb = wsu + 66500000;        // 221*512 = 113,152 ushorts
  float* fo = (float*)(wsu + 67000000);

  ushort* xt = R0;
  ushort* h1 = R1;
  ushort* h2 = R0;
  ushort* h3 = R1;
  ushort* h4 = R0;
  ushort* h5 = R1;

  ushort* B1 = Bgb;                 // 16 chunks
  ushort* B2 = Bgb + 16 * 512;      // 48
  ushort* B3 = Bgb + 64 * 512;      // 48
  ushort* B4 = Bgb + 112 * 512;     // 64
  ushort* B5 = Bgb + 176 * 512;     // 45

  build_b<1, 3, 4, 5><<<16, 256, 0, stream>>>(w1, B1);
  build_b<3, 3, 4, 4><<<48, 256, 0, stream>>>(w2, B2);
  build_b<3, 4, 4, 3><<<48, 256, 0, stream>>>(w3, B3);
  build_b<4, 5, 4, 3><<<64, 256, 0, stream>>>(w4, B4);
  build_b<5, 5, 3, 2><<<45, 256, 0, stream>>>(w5, B5);

  const int P = 104976;  // 18^4
  transpose_kernel<<<dim3((P + 63) / 64, 4), 256, 0, stream>>>(x, xt, P);

  // <CIN,COUT,KK,TI,S,HB>  grid(x = wt*HTILES+ht, y = d, z = t)
  conv_mfma<1, 3, 4, 18, 5, 3><<<dim3(15, 15, 15), 256, 0, stream>>>(xt, B1, b1, h1);
  conv_mfma<3, 3, 4, 15, 4, 3><<<dim3(12, 12, 12), 256, 0, stream>>>(h1, B2, b2, h2);
  conv_mfma<3, 4, 4, 12, 3, 3><<<dim3(9, 9, 9), 256, 0, stream>>>(h2, B3, b3, h3);
  conv_mfma<4, 5, 4, 9, 3, 1><<<dim3(12, 6, 6), 256, 0, stream>>>(h3, B4, b4, h4);
  conv_mfma<5, 5, 3, 6, 2, 2><<<dim3(4, 4, 4), 256, 0, stream>>>(h4, B5, b5, h5);

  fc1_kernel<<<33, 256, 0, stream>>>(h5, fc1w, fc1b, fo);
  fc2_kernel<<<1, 256, 0, stream>>>(fo, fc2w, fc2b, out);
}